// Round 12
// baseline (334.815 us; speedup 1.0000x reference)
//
#include <hip/hip_runtime.h>

#define SEQ_LEN 2048
#define BATCH   512
#define HIDDEN  25

typedef int v2i __attribute__((ext_vector_type(2)));
typedef _Float16 h2_t __attribute__((ext_vector_type(2)));

__device__ __forceinline__ float fast_rcp(float v)  { return __builtin_amdgcn_rcpf(v); }
__device__ __forceinline__ float fast_exp2(float v) { return __builtin_amdgcn_exp2f(v); }

// D = a.lo*b.lo + a.hi*b.hi + c, f16 multiply / f32 accumulate
__device__ __forceinline__ float fdot2i(int a, int b, float c) {
#if __has_builtin(__builtin_amdgcn_fdot2)
    return __builtin_amdgcn_fdot2(__builtin_bit_cast(h2_t, a), __builtin_bit_cast(h2_t, b), c, false);
#else
    float d;
    asm("v_dot2_f32_f16 %0, %1, %2, %3" : "=v"(d) : "v"(a), "v"(b), "v"(c));
    return d;
#endif
}

// v_permlane32_swap(v,v): new_vdst = {lanes<32: own value, lanes>=32: v[lane-32]}.
// Consumed ONLY on U lanes (cs update), where r.x == L's value.
__device__ __forceinline__ float xswap_rx(float v) {
#if __has_builtin(__builtin_amdgcn_permlane32_swap)
    v2i r = __builtin_amdgcn_permlane32_swap(__float_as_int(v), __float_as_int(v), false, false);
    return __int_as_float(r.x);
#else
    return __shfl_xor(v, 32);   // superset: correct on U lanes too
#endif
}

// One wave per batch element (R5/R10 structure).
//   L lane j  (0..24):  rows j (i, sigmoid) and 50+j (g, tanh)  -> i*g local
//   U lane 32+j (0..24): rows 25+j (f) and 75+j (o); owns c_j, h_j
// h crosses as packed-f16 pairs via 13 readlanes.
// R11 delta: MERGED GATE RECIPROCAL. With e1=exp2(a1), e2=exp2(a2),
// A=1+e1, B=1+e2, one r=rcp(A*B) yields R1=B*r=1/A and R2=A*r=1/B —
// 5 transcendentals/step instead of 6 (the exact-math floor: 2 exp2 for
// 100 gate values, 1 merged rcp, exp2+rcp for tanh(c)). Measured model:
// trans ops occupy ~29cy each at wave64, so -1 trans ~= -29cy/step.
__global__ __launch_bounds__(64)
__attribute__((amdgpu_waves_per_eu(1, 1)))
void lstm_kernel(
    const float* __restrict__ x,
    const float* __restrict__ W_ih,
    const float* __restrict__ W_hh,
    const float* __restrict__ b_ih,
    const float* __restrict__ b_hh,
    const float* __restrict__ W_lin,
    const float* __restrict__ b_lin,
    float* __restrict__ out)
{
    const int lane = threadIdx.x;
    const int b    = blockIdx.x;

    __shared__ float pp[64][29];   // deferred output partials; 29 coprime w/ 32 banks

    const bool U  = (lane >= 32);
    const int  j  = lane & 31;
    const int  jj = (j < HIDDEN) ? j : 0;          // clamp idle lanes to a harmless row
    const bool hv = (j < HIDDEN);

    const int r1 = U ? (HIDDEN + jj) : jj;                     // f : i  (sigmoid)
    const int r2 = U ? (3 * HIDDEN + jj) : (2 * HIDDEN + jj);  // o : g

    const float LOG2E = 1.4426950408889634f;
    const float s1 = -LOG2E;                       // sigmoid pre-scale
    const float s2 = U ? -LOG2E : (-2.0f * LOG2E); // o: sigmoid, g: tanh(=sig(2x))

    // fold scales into weights, pad k=25 with 0, pack to f16 pairs
    float w1[26], w2[26];
    #pragma unroll
    for (int k = 0; k < HIDDEN; ++k) {
        w1[k] = W_hh[r1 * HIDDEN + k] * s1;
        w2[k] = W_hh[r2 * HIDDEN + k] * s2;
    }
    w1[25] = 0.0f; w2[25] = 0.0f;
    int W1p[13], W2p[13];
    #pragma unroll
    for (int m = 0; m < 13; ++m) {
        W1p[m] = __builtin_bit_cast(int, __builtin_amdgcn_cvt_pkrtz(w1[2*m], w1[2*m+1]));
        W2p[m] = __builtin_bit_cast(int, __builtin_amdgcn_cvt_pkrtz(w2[2*m], w2[2*m+1]));
    }
    float bias1 = (b_ih[r1] + b_hh[r1]) * s1;
    float bias2 = (b_ih[r2] + b_hh[r2]) * s2;
    float wi1   = W_ih[r1] * s1;
    float wi2   = W_ih[r2] * s2;

    // pin loop-invariants into VGPRs (defeat remat/spill)
    #pragma unroll
    for (int m = 0; m < 13; ++m) {
        asm volatile("" : "+v"(W1p[m]));
        asm volatile("" : "+v"(W2p[m]));
    }
    asm volatile("" : "+v"(bias1), "+v"(bias2), "+v"(wi1), "+v"(wi2));

    const float wlin  = (U && hv) ? W_lin[jj] : 0.0f;
    const float blin  = b_lin[0];
    const int   pcol  = (U && hv) ? jj : 26;       // inactive lanes -> unused col

    float cs = 0.0f;   // c' = -2log2e * c   (real on U lanes)
    float vh = 0.0f;   // h                  (real on U lanes)

    const float* xb = x + b;
    float xv = xb[(size_t)lane * BATCH];           // x[t=lane][b], staggered prefetch

    #pragma unroll 1
    for (int tb = 0; tb < SEQ_LEN; tb += 64) {
        float xv_next = 0.0f;
        if (tb + 64 < SEQ_LEN) xv_next = xb[(size_t)(tb + 64 + lane) * BATCH];

        #pragma unroll 4
        for (int tt = 0; tt < 64; ++tt) {
            // pack {h_j, h_{j^1}} as f16x2 (valid on even U lanes)
            const int vhn = __builtin_amdgcn_mov_dpp(__float_as_int(vh), 0xB1, 0xF, 0xF, true);
            const int hpk = __builtin_bit_cast(int,
                __builtin_amdgcn_cvt_pkrtz(vh, __int_as_float(vhn)));

            // broadcast 25 h values as 13 packed words from even U lanes
            int hw[13];
            #pragma unroll
            for (int m = 0; m < 13; ++m)
                hw[m] = __builtin_amdgcn_readlane(hpk, 32 + 2 * m);

            const float xt = __int_as_float(__builtin_amdgcn_readlane(__float_as_int(xv), tt));

            // 3 accumulator chains per gate row (depth 5/5/3)
            float a1 = fmaf(xt, wi1, bias1);
            float a2 = fmaf(xt, wi2, bias2);
            float p1 = 0.0f, q1 = 0.0f;
            float p2 = 0.0f, q2 = 0.0f;
            #pragma unroll
            for (int m = 0; m < 5; ++m) {
                a1 = fdot2i(W1p[m], hw[m], a1);
                a2 = fdot2i(W2p[m], hw[m], a2);
            }
            #pragma unroll
            for (int m = 5; m < 10; ++m) {
                p1 = fdot2i(W1p[m], hw[m], p1);
                p2 = fdot2i(W2p[m], hw[m], p2);
            }
            #pragma unroll
            for (int m = 10; m < 13; ++m) {
                q1 = fdot2i(W1p[m], hw[m], q1);
                q2 = fdot2i(W2p[m], hw[m], q2);
            }
            a1 = (a1 + p1) + q1;
            a2 = (a2 + p2) + q2;

            // merged gate reciprocal: one rcp for both sigmoids
            const float e1 = fast_exp2(a1);
            const float e2 = fast_exp2(a2);
            const float A  = 1.0f + e1;
            const float B  = 1.0f + e2;
            const float r  = fast_rcp(A * B);
            const float R1 = B * r;                // 1/A: i (L) / f (U)
            const float R2 = A * r;                // 1/B: sig(2zg) (L) / o (U)

            // L: igs = i * g * (-2log2e), where g = 2*R2 - 1
            const float Gp  = fmaf(R2, -4.0f * LOG2E, 2.0f * LOG2E);
            const float igs = R1 * Gp;
            const float igx = xswap_rx(igs);       // U lanes receive L's igs (r.x)

            cs = fmaf(R1, cs, igx);                // c' = f*c' + (-2log2e)*i*g  (U)
            const float R3 = fast_rcp(1.0f + fast_exp2(cs));   // sig(2c) -> tanh(c)=2R3-1
            const float o2 = R2 + R2;              // 2o (off critical path)
            vh = fmaf(o2, R3, -R2);                // h = o*tanh(c) = 2o*R3 - o  (U)

            pp[tt][pcol] = vh * wlin;              // deferred output partial
        }
        // single-wave block: same-wave LDS ops are in program order -> no barrier
        float s = blin;
        #pragma unroll
        for (int k = 0; k < HIDDEN; ++k) s += pp[lane][k];
        out[(size_t)(tb + lane) * BATCH + b] = s;

        xv = xv_next;
    }
}

extern "C" void kernel_launch(void* const* d_in, const int* in_sizes, int n_in,
                              void* d_out, int out_size, void* d_ws, size_t ws_size,
                              hipStream_t stream) {
    const float* x     = (const float*)d_in[0];
    const float* W_ih  = (const float*)d_in[1];
    const float* W_hh  = (const float*)d_in[2];
    const float* b_ih  = (const float*)d_in[3];
    const float* b_hh  = (const float*)d_in[4];
    const float* W_lin = (const float*)d_in[5];
    const float* b_lin = (const float*)d_in[6];
    float* outp = (float*)d_out;

    hipLaunchKernelGGL(lstm_kernel, dim3(BATCH), dim3(64), 0, stream,
                       x, W_ih, W_hh, b_ih, b_hh, W_lin, b_lin, outp);
}

// Round 14
// 324.997 us; speedup vs baseline: 1.0302x; 1.0302x over previous
//
#include <hip/hip_runtime.h>

#define SEQ_LEN 2048
#define BATCH   512
#define HIDDEN  25

typedef int v2i __attribute__((ext_vector_type(2)));
typedef _Float16 h2_t __attribute__((ext_vector_type(2)));

__device__ __forceinline__ float fast_rcp(float v)  { return __builtin_amdgcn_rcpf(v); }
__device__ __forceinline__ float fast_exp2(float v) { return __builtin_amdgcn_exp2f(v); }

// D = a.lo*b.lo + a.hi*b.hi + c, f16 multiply / f32 accumulate
__device__ __forceinline__ float fdot2i(int a, int b, float c) {
#if __has_builtin(__builtin_amdgcn_fdot2)
    return __builtin_amdgcn_fdot2(__builtin_bit_cast(h2_t, a), __builtin_bit_cast(h2_t, b), c, false);
#else
    float d;
    asm("v_dot2_f32_f16 %0, %1, %2, %3" : "=v"(d) : "v"(a), "v"(b), "v"(c));
    return d;
#endif
}

// One wave per batch element. j-PAIR layout (R12, fixed):
//   lane 2j   (j=0..24): rows j      (i, sigmoid) and 50+j (g, tanh)
//   lane 2j+1 (j=0..24): rows 25+j   (f, sigmoid) and 75+j (o, sigmoid);
//                        owns c_j, h_j
// i*g crosses even->odd via mov_dpp ROW_SHR:1 (0x111): lane i receives lane
// i-1's value (R12 bug: 0x101=row_shl:1 is lane i+1 — neighbor-swapped LSTM).
// h-pack: lane 4m+1 packs {own h_2m, quad-lane-3's h_2m+1} via quad_perm;
// 13 readlanes broadcast from lanes 4m+1. Lanes 50..63 idle (clamped).
__global__ __launch_bounds__(64)
__attribute__((amdgpu_waves_per_eu(1, 1)))
void lstm_kernel(
    const float* __restrict__ x,
    const float* __restrict__ W_ih,
    const float* __restrict__ W_hh,
    const float* __restrict__ b_ih,
    const float* __restrict__ b_hh,
    const float* __restrict__ W_lin,
    const float* __restrict__ b_lin,
    float* __restrict__ out)
{
    const int lane = threadIdx.x;
    const int b    = blockIdx.x;

    __shared__ float pp[64][29];   // deferred output partials; 29 coprime w/ 32 banks

    const bool odd = (lane & 1);
    const int  j   = lane >> 1;                    // hidden index of this pair
    const int  jj  = (j < HIDDEN) ? j : 0;         // clamp idle lanes 50..63
    const bool hv  = (j < HIDDEN);

    const int r1 = odd ? (HIDDEN + jj) : jj;                     // f : i (sigmoid)
    const int r2 = odd ? (3 * HIDDEN + jj) : (2 * HIDDEN + jj);  // o : g

    const float LOG2E = 1.4426950408889634f;
    const float s1 = -LOG2E;                         // sigmoid pre-scale
    const float s2 = odd ? -LOG2E : (-2.0f * LOG2E); // o: sigmoid, g: tanh(=sig(2x))

    // fold scales into weights, pad k=25 with 0, pack to f16 pairs
    float w1[26], w2[26];
    #pragma unroll
    for (int k = 0; k < HIDDEN; ++k) {
        w1[k] = W_hh[r1 * HIDDEN + k] * s1;
        w2[k] = W_hh[r2 * HIDDEN + k] * s2;
    }
    w1[25] = 0.0f; w2[25] = 0.0f;
    int W1p[13], W2p[13];
    #pragma unroll
    for (int m = 0; m < 13; ++m) {
        W1p[m] = __builtin_bit_cast(int, __builtin_amdgcn_cvt_pkrtz(w1[2*m], w1[2*m+1]));
        W2p[m] = __builtin_bit_cast(int, __builtin_amdgcn_cvt_pkrtz(w2[2*m], w2[2*m+1]));
    }
    float bias1 = (b_ih[r1] + b_hh[r1]) * s1;
    float bias2 = (b_ih[r2] + b_hh[r2]) * s2;
    float wi1   = W_ih[r1] * s1;
    float wi2   = W_ih[r2] * s2;

    // pin loop-invariants into VGPRs (defeat remat/spill)
    #pragma unroll
    for (int m = 0; m < 13; ++m) {
        asm volatile("" : "+v"(W1p[m]));
        asm volatile("" : "+v"(W2p[m]));
    }
    asm volatile("" : "+v"(bias1), "+v"(bias2), "+v"(wi1), "+v"(wi2));

    const float wlin  = (odd && hv) ? W_lin[jj] : 0.0f;
    const float blin  = b_lin[0];
    const int   pcol  = (odd && hv) ? jj : 26;     // inactive lanes -> unused col

    float cs = 0.0f;   // c' = -2log2e * c   (real on odd lanes)
    float vh = 0.0f;   // h                  (real on odd lanes)

    const float* xb = x + b;
    float xv = xb[(size_t)lane * BATCH];           // x[t=lane][b], staggered prefetch

    #pragma unroll 1
    for (int tb = 0; tb < SEQ_LEN; tb += 64) {
        float xv_next = 0.0f;
        if (tb + 64 < SEQ_LEN) xv_next = xb[(size_t)(tb + 64 + lane) * BATCH];

        #pragma unroll 4
        for (int tt = 0; tt < 64; ++tt) {
            // pack {h_2m, h_2m+1}: lane 4m+1 pairs own vh with quad lane 3's vh
            const int nb  = __builtin_amdgcn_mov_dpp(__float_as_int(vh), 0xFF, 0xF, 0xF, true); // quad_perm[3,3,3,3]
            const int hpk = __builtin_bit_cast(int,
                __builtin_amdgcn_cvt_pkrtz(vh, __int_as_float(nb)));

            // broadcast 25 h values as 13 packed words from lanes 4m+1
            int hw[13];
            #pragma unroll
            for (int m = 0; m < 13; ++m)
                hw[m] = __builtin_amdgcn_readlane(hpk, 4 * m + 1);

            const float xt = __int_as_float(__builtin_amdgcn_readlane(__float_as_int(xv), tt));

            // 3 accumulator chains per gate row (depth 5/5/3)
            float a1 = fmaf(xt, wi1, bias1);
            float a2 = fmaf(xt, wi2, bias2);
            float p1 = 0.0f, q1 = 0.0f;
            float p2 = 0.0f, q2 = 0.0f;
            #pragma unroll
            for (int m = 0; m < 5; ++m) {
                a1 = fdot2i(W1p[m], hw[m], a1);
                a2 = fdot2i(W2p[m], hw[m], a2);
            }
            #pragma unroll
            for (int m = 5; m < 10; ++m) {
                p1 = fdot2i(W1p[m], hw[m], p1);
                p2 = fdot2i(W2p[m], hw[m], p2);
            }
            #pragma unroll
            for (int m = 10; m < 13; ++m) {
                q1 = fdot2i(W1p[m], hw[m], q1);
                q2 = fdot2i(W2p[m], hw[m], q2);
            }
            a1 = (a1 + p1) + q1;
            a2 = (a2 + p2) + q2;

            // parallel gate activations (rcp pair is one latency quantum)
            const float R1 = fast_rcp(1.0f + fast_exp2(a1));   // i (even) / f (odd)
            const float R2 = fast_rcp(1.0f + fast_exp2(a2));   // sig(2zg) (even) / o (odd)

            // even: igs = i * g * (-2log2e), g = 2*R2 - 1
            const float Gp  = fmaf(R2, -4.0f * LOG2E, 2.0f * LOG2E);
            const float igs = R1 * Gp;
            // odd lane 2j+1 receives even lane 2j's igs: ROW_SHR:1 = 0x111
            const float igx = __int_as_float(
                __builtin_amdgcn_mov_dpp(__float_as_int(igs), 0x111, 0xF, 0xF, true));

            cs = fmaf(R1, cs, igx);                // c' = f*c' + (-2log2e)*i*g  (odd)
            const float R3 = fast_rcp(1.0f + fast_exp2(cs));   // sig(2c): tanh(c)=2R3-1
            const float o2 = R2 + R2;              // 2o (off critical path)
            vh = fmaf(o2, R3, -R2);                // h = o*tanh(c) = 2o*R3 - o  (odd)

            pp[tt][pcol] = vh * wlin;              // deferred output partial
        }
        // single-wave block: same-wave LDS ops are in program order -> no barrier
        float s = blin;
        #pragma unroll
        for (int k = 0; k < HIDDEN; ++k) s += pp[lane][k];
        out[(size_t)(tb + lane) * BATCH + b] = s;

        xv = xv_next;
    }
}

extern "C" void kernel_launch(void* const* d_in, const int* in_sizes, int n_in,
                              void* d_out, int out_size, void* d_ws, size_t ws_size,
                              hipStream_t stream) {
    const float* x     = (const float*)d_in[0];
    const float* W_ih  = (const float*)d_in[1];
    const float* W_hh  = (const float*)d_in[2];
    const float* b_ih  = (const float*)d_in[3];
    const float* b_hh  = (const float*)d_in[4];
    const float* W_lin = (const float*)d_in[5];
    const float* b_lin = (const float*)d_in[6];
    float* outp = (float*)d_out;

    hipLaunchKernelGGL(lstm_kernel, dim3(BATCH), dim3(64), 0, stream,
                       x, W_ih, W_hh, b_ih, b_hh, W_lin, b_lin, outp);
}